// Round 8
// baseline (354.308 us; speedup 1.0000x reference)
//
#include <hip/hip_runtime.h>
#include <hip/hip_bf16.h>

typedef __attribute__((ext_vector_type(8))) short short8;   // 8 bf16 (4 VGPRs)
typedef __attribute__((ext_vector_type(4))) float f32x4;    // MFMA acc

#define NH   4
#define NB   1024
#define NL   200
#define NDQ  512
#define NDF  128
#define ND1  128
#define ND2  64
#define KP   128            // k-stride (bf16 elems); conflicts handled by rotation swizzle
#define NW   13             // active warps = M-tiles (13*16 = 208 >= 200 rows)
#define NT   (NW*64)        // 832 threads
#define HIMG (3*ND2*KP*2)   // bytes per head weight image (49152)
#define SGRAN (3*ND2*16)    // 3072 float4 granules per head image
#define KC_GRID (1024 + 256 + 3)   // k_combine blocks: Wqc splitK | Wfc/Wvc | biases

// workspace layout (bytes)
#define OFF_WQC   0                                    // fp32 [H][512][64]   524288
#define OFF_BQC   (NH*NDQ*ND2*4)                       // fp32 [H][64]
#define OFF_FQ    (OFF_BQC + NH*ND2*4)                 // (unused now; kept for layout stability)
#define OFF_WIMG  (OFF_FQ + NH*NB*ND2*4)               // bf16 [H][3][64][KP] (slots: Wf_hi, Wf_lo, Wv_hi)
#define OFF_BFC   (OFF_WIMG + NH*HIMG)                 // fp32 [H][64]
#define OFF_BVC   (OFF_BFC + NH*ND2*4)                 // fp32 [H][64]

// global->LDS DMA: per-lane GLOBAL address, wave-uniform LDS base + lane*16
#define GLOAD_LDS16(gp, lp) __builtin_amdgcn_global_load_lds(                 \
    (const __attribute__((address_space(1))) void*)(gp),                      \
    (__attribute__((address_space(3))) void*)(lp), 16, 0, 0)

__device__ inline short f2bf(float f) {                // RN-even fp32 -> bf16 bits
    union { float f; unsigned u; } v; v.f = f;
    unsigned r = (v.u + 0x7FFFu + ((v.u >> 16) & 1u)) >> 16;
    return (short)r;
}
__device__ inline float bf2f(short s) {
    union { unsigned u; float f; } v; v.u = ((unsigned)(unsigned short)s) << 16;
    return v.f;
}
__device__ inline float fsilu(float z) {               // fast silu
    return z * __fdividef(1.f, 1.f + __expf(-z));
}

// ---- cross-lane reductions on the VALU (no DS pipe) ----
template<int CTRL>
__device__ inline float dppf(float x) {                // DPP-moved copy of x
    return __int_as_float(__builtin_amdgcn_update_dpp(0, __float_as_int(x), CTRL, 0xF, 0xF, true));
}
__device__ inline float red16_add(float s) {
    s += dppf<0xB1>(s);      // quad_perm [1,0,3,2]  (xor1)
    s += dppf<0x4E>(s);      // quad_perm [2,3,0,1]  (xor2)
    s += dppf<0x141>(s);     // row_half_mirror
    s += dppf<0x140>(s);     // row_mirror
    return s;
}
__device__ inline float swap16_add(float x) {
    auto p = __builtin_amdgcn_permlane16_swap(__float_as_uint(x), __float_as_uint(x), false, false);
    return __uint_as_float(p[0]) + __uint_as_float(p[1]);
}
__device__ inline float swap32_add(float x) {
    auto p = __builtin_amdgcn_permlane32_swap(__float_as_uint(x), __float_as_uint(x), false, false);
    return __uint_as_float(p[0]) + __uint_as_float(p[1]);
}
__device__ inline float swap16_max(float x) {
    auto p = __builtin_amdgcn_permlane16_swap(__float_as_uint(x), __float_as_uint(x), false, false);
    return fmaxf(__uint_as_float(p[0]), __uint_as_float(p[1]));
}
__device__ inline float swap32_max(float x) {
    auto p = __builtin_amdgcn_permlane32_swap(__float_as_uint(x), __float_as_uint(x), false, false);
    return fmaxf(__uint_as_float(p[0]), __uint_as_float(p[1]));
}

// ---------------- K1: fuse weights (identity between FC layers) ----------------
// Block families: [0,1024) Wqc with 2-way split-K; [1024,1280) Wfc/Wvc images;
// [1280,1283) fused biases.
__global__ __launch_bounds__(256) void k_combine(
    const float* __restrict__ Wq1, const float* __restrict__ bq1,
    const float* __restrict__ Wq2, const float* __restrict__ bq2,
    const float* __restrict__ Wf1, const float* __restrict__ bf1,
    const float* __restrict__ Wf2, const float* __restrict__ bf2,
    const float* __restrict__ Wv1, const float* __restrict__ bv1,
    const float* __restrict__ Wv2, const float* __restrict__ bv2,
    float* __restrict__ WQC, float* __restrict__ BQC,
    __hip_bfloat16* __restrict__ WIMG, float* __restrict__ BFC, float* __restrict__ BVC)
{
    __shared__ float part[256];
    const int blk = blockIdx.x, t = threadIdx.x;
    if (blk < 1024) {                           // Wqc = Wq1@Wq2 (fp32), split-K x2
        int o = blk*128 + (t & 127);            // output index in [0, 131072)
        int kh = t >> 7;                        // K-half
        int h = o >> 15, r = o & 32767, i = r >> 6, j = r & 63;
        const float* a  = Wq1 + (h*NDQ + i)*ND1 + kh*64;
        const float* bb = Wq2 + h*ND1*ND2 + kh*64*ND2 + j;
        float s = 0.f;
        #pragma unroll 16
        for (int k = 0; k < 64; ++k) s += a[k] * bb[k*ND2];
        part[t] = s;
        __syncthreads();
        if (t < 128) WQC[o] = part[t] + part[t + 128];
        return;
    }
    if (blk < 1280) {                           // Wfc (hi+lo) / Wvc (hi), transposed image
        int g = (blk - 1024)*256 + t;           // 0..65535
        int which = (g >= NH*NDF*ND2);
        int r0 = g & (NH*NDF*ND2 - 1);
        int h = r0 >> 13, r = r0 & 8191, i = r >> 6, j = r & 63;
        const float* W1 = (which ? Wv1 : Wf1) + (h*NDF + i)*ND1;
        const float* W2 = (which ? Wv2 : Wf2) + h*ND1*ND2 + j;
        float s = 0.f;
        #pragma unroll 16
        for (int k = 0; k < ND1; ++k) s += W1[k] * W2[k*ND2];
        short hi = f2bf(s);
        short lo = f2bf(s - bf2f(hi));
        __hip_bfloat16* img = WIMG + (size_t)((h*3 + (which ? 2 : 0))*ND2 + j)*KP + i; // [col=j][k=i]
        ((short*)img)[0] = hi;
        if (!which) ((short*)img)[ND2*KP] = lo;  // Wf lo slot
        return;
    }
    int g = (blk - 1280)*256 + t;               // 0..767: fused biases
    int h = (g >> 6) & 3, j = g & 63;
    if (g < NH*ND2) {                           // bqc = bq1@Wq2 + bq2
        float s = bq2[h*ND2 + j];
        for (int k = 0; k < ND1; ++k) s += bq1[h*ND1 + k] * Wq2[(h*ND1 + k)*ND2 + j];
        BQC[g] = s;
    } else if (g < 2*NH*ND2) {
        float s = bf2[h*ND2 + j];
        for (int k = 0; k < ND1; ++k) s += bf1[h*ND1 + k] * Wf2[(h*ND1 + k)*ND2 + j];
        BFC[h*ND2 + j] = s;
    } else if (g < 3*NH*ND2) {
        float s = bv2[h*ND2 + j];
        for (int k = 0; k < ND1; ++k) s += bv1[h*ND1 + k] * Wv2[(h*ND1 + k)*ND2 + j];
        BVC[h*ND2 + j] = s;
    }
}

// ---------------- K2: main fused attention (fq folded into prologue) ----------------
// 832 threads (13 warps), one M-tile/warp, one b per block.
// Prologue additionally computes fq[h][d] = silu(q[b]@WQC[h] + bqc) via 12-wave
// 3-way split-K (fp32) -> fqS, overlapped with weight DMA + A-convert. This
// deletes the separate k_fq kernel and its serialization.
// All cross-lane reductions are VALU (DPP + permlane swaps); weight staging
// via global_load_lds DMA (inverse-rotation-swizzled source, conflict-free
// reads), double-buffered; swizzled LDS byte-offsets precomputed once.
__global__ __launch_bounds__(NT) __attribute__((amdgpu_waves_per_eu(4, 4))) void k_main(
    const float* __restrict__ fact,
    const int* __restrict__ mask,
    const float* __restrict__ mmc,
    const float* __restrict__ tau1,
    const float* __restrict__ tau2,
    const float* __restrict__ query,
    const float* __restrict__ WQC,
    const float* __restrict__ BQC,
    const float* __restrict__ BFC,
    const float* __restrict__ BVC,
    const __hip_bfloat16* __restrict__ WIMG,
    float* __restrict__ out)
{
    __shared__ __align__(16) __hip_bfloat16 wS[2][3*ND2*KP];  // 2 x 49152 B
    __shared__ __align__(16) float pS[2][NW][132];            // ping-pong: m, s, oE[64], oS[64]
    __shared__ __align__(16) float fqP[3][256];               // fq split-K partials
    __shared__ __align__(16) float fqS[NH][ND2];              // 1 KB
    __shared__ __align__(16) float bfcS[NH][ND2];             // 1 KB
    __shared__ __align__(16) float bvcS[NH][ND2];             // 1 KB

    const int t    = threadIdx.x;
    const int b    = blockIdx.x;
    const int w    = t >> 6;                    // 0..12 = M-tile index
    const int lane = t & 63;
    const int a15  = lane & 15;
    const int quad = lane >> 4;
    const int qrot = quad + 2*(a15 & 7);        // read-side swizzle base

    const int bL = b * NL;

    // ---- DMA staging setup: wave w owns float4-chunks w*4..w*4+3 (<48).
    //      LDS slot i = c*64 + lane receives global granule row*16 + g with
    //      g = ((i&15) - 2*(row&7)) & 15, row = i>>4  (inverse of the swizzle).
    int srcOff[4], ldsByte[4];
    bool cOk[4];
    #pragma unroll
    for (int j = 0; j < 4; ++j) {
        int c = w*4 + j;
        cOk[j] = (c < SGRAN/64);
        int i = c*64 + lane;
        int row = i >> 4, gp = i & 15;
        int g = (gp - 2*(row & 7)) & 15;
        srcOff[j] = (row*16 + g) * 16;          // bytes within head image
        ldsByte[j] = c * 1024;                  // wave-uniform LDS base (bytes)
    }
    // ---- issue head-0 DMA immediately (hides under prologue) ----
    #pragma unroll
    for (int j = 0; j < 4; ++j)
        if (cOk[j])
            GLOAD_LDS16((const char*)WIMG + srcOff[j], (char*)&wS[0][0] + ldsByte[j]);

    // ---- swizzled LDS byte offsets for the GEMM B-reads (precomputed once) ----
    int ldsOff[16];
    #pragma unroll
    for (int kk = 0; kk < 4; ++kk)
        #pragma unroll
        for (int nt = 0; nt < 4; ++nt)
            ldsOff[kk*4 + nt] = (((nt*16 + a15)*KP) + (((kk*4 + qrot) & 15) << 3)) * 2;

    // ---- per-head constant loads (BFC/BVC -> LDS) ----
    float cv0 = 0.f;
    if (t < 256)       cv0 = BFC[t];
    else if (t < 512)  cv0 = BVC[t - 256];
    // ---- head-invariant per-row data (mask penalty + cosine terms) ----
    float mkv[4], c0v[4], c1v[4];
    {
        int rbase = w*16 + quad*4;
        for (int rg = 0; rg < 4; ++rg) {
            int r = rbase + rg;
            if (r < NL) {
                mkv[rg] = 1e9f * (1.0f - (float)mask[bL + r]);
                c0v[rg] = mmc[bL + r];
                c1v[rg] = mmc[NB*NL + bL + r];
            } else { mkv[rg] = 0.f; c0v[rg] = 0.f; c1v[rg] = 0.f; }
        }
    }

    // ---- A fragments: this warp's 16 fact rows, hi/lo bf16 ----
    short8 afh[4], afl[4];
    const short8 zero8 = {0,0,0,0,0,0,0,0};
    {
        int row = w*16 + a15;
        for (int kk = 0; kk < 4; ++kk) {
            short8 vh = zero8, vl = zero8;
            if (row < NL) {
                const float* p = fact + ((size_t)(bL + row))*NDF + kk*32 + quad*8;
                float4 x0 = *(const float4*)p;
                float4 x1 = *(const float4*)(p + 4);
                float v[8] = {x0.x, x0.y, x0.z, x0.w, x1.x, x1.y, x1.z, x1.w};
                for (int j = 0; j < 8; ++j) {
                    short hs = f2bf(v[j]);
                    vh[j] = hs;
                    vl[j] = f2bf(v[j] - bf2f(hs));
                }
            }
            afh[kk] = vh;
            afl[kk] = vl;
        }
    }

    if (t < 256)       ((float*)bfcS)[t]       = cv0;
    else if (t < 512)  ((float*)bvcS)[t - 256] = cv0;

    // ---- fq split-K partials: 12 waves, wave = (h, K-third), d = lane ----
    if (t < 768) {
        const int third = t >> 8;               // 0..2
        const int o     = t & 255;              // h*64 + d
        const int hq    = o >> 6, dq = o & 63;
        const int i0    = third * 171;
        const int len   = (third == 2) ? 170 : 171;
        const float* qp = query + (size_t)b*NDQ + i0;
        const float* wp = WQC + ((size_t)hq*NDQ + i0)*ND2 + dq;
        float s = 0.f;
        #pragma unroll 8
        for (int i = 0; i < len; ++i) s += qp[i] * wp[i*ND2];
        fqP[third][o] = s;
    }
    __syncthreads();                            // fqP/bfcS/bvcS ready (DMA also drains)
    if (t < 256)
        ((float*)fqS)[t] = fsilu(fqP[0][t] + fqP[1][t] + fqP[2][t] + BQC[t]);
    __syncthreads();                            // fqS + wS[0] ready

    const f32x4 zf = {0.f, 0.f, 0.f, 0.f};

    for (int h = 0; h < NH; ++h) {
        // ---- issue next-head DMA first (latency hides under compute) ----
        if (h + 1 < NH) {
            const char* hb = (const char*)WIMG + (size_t)(h+1)*HIMG;
            char* lb = (char*)&wS[(h+1) & 1][0];
            #pragma unroll
            for (int j = 0; j < 4; ++j)
                if (cOk[j]) GLOAD_LDS16(hb + srcOff[j], lb + ldsByte[j]);
        }
        // ---- merge of previous head by one dedicated warp (9..11) ----
        if (h > 0 && w == 8 + h) {
            const int ps = (h - 1) & 1;
            float M = pS[ps][0][0];
            for (int ww = 1; ww < NW; ++ww) M = fmaxf(M, pS[ps][ww][0]);
            float den = 0.f, num = 0.f, s1 = 0.f;
            for (int ww = 0; ww < NW; ++ww) {
                float e = __expf(pS[ps][ww][0] - M);
                den += e * pS[ps][ww][1];
                num += e * pS[ps][ww][2 + lane];
                s1  += pS[ps][ww][66 + lane];
            }
            out[(size_t)b*(NH*ND2) + (h-1)*ND2 + lane] = num * __fdividef(1.f, den) + 1e-7f * s1;
        }

        const float rt1a = __fdividef(1.f, tau1[h]);
        const float rt1b = __fdividef(1.f, tau1[NH + h]);
        const float t20 = tau2[h];
        const float t21 = tau2[NH + h];
        const float t22 = tau2[2*NH + h];

        float fqv[4], bfcv[4];
        for (int nt = 0; nt < 4; ++nt) {
            fqv[nt]  = fqS[h][nt*16 + a15];
            bfcv[nt] = bfcS[h][nt*16 + a15];
        }

        const char* wbc = (const char*)&wS[h & 1][0];

        // ---- ff GEMM, 3 passes: f_hi*w_hi + f_hi*w_lo + f_lo*w_hi ----
        f32x4 acc[4];
        for (int nt = 0; nt < 4; ++nt) acc[nt] = zf;
        __builtin_amdgcn_s_setprio(1);
        for (int kk = 0; kk < 4; ++kk) {
            short8 bh[4], bl[4];
            for (int nt = 0; nt < 4; ++nt) {
                const char* p = wbc + ldsOff[kk*4 + nt];
                bh[nt] = *(const short8*)p;
                bl[nt] = *(const short8*)(p + 16384);   // Wf_lo slot
            }
            for (int nt = 0; nt < 4; ++nt) {
                acc[nt] = __builtin_amdgcn_mfma_f32_16x16x32_bf16(afh[kk], bh[nt], acc[nt], 0, 0, 0);
                acc[nt] = __builtin_amdgcn_mfma_f32_16x16x32_bf16(afh[kk], bl[nt], acc[nt], 0, 0, 0);
                acc[nt] = __builtin_amdgcn_mfma_f32_16x16x32_bf16(afl[kk], bh[nt], acc[nt], 0, 0, 0);
            }
        }
        __builtin_amdgcn_s_setprio(0);

        // ---- epilogue: silu, dot with fq (DPP row reduce), mask+bias -> logits ----
        float lg[4];
        for (int rg = 0; rg < 4; ++rg) {
            float l = -3.0e38f;
            float s = 0.f;
            for (int nt = 0; nt < 4; ++nt)
                s += fsilu(acc[nt][rg] + bfcv[nt]) * fqv[nt];
            s = red16_add(s);
            int r = w*16 + quad*4 + rg;
            if (r < NL) {
                float dv = s - mkv[rg];
                float bias = c0v[rg]*rt1a + c1v[rg]*rt1b;
                l = t20*dv + t21*bias + t22*dv*bias;
            }
            lg[rg] = l;
        }

        // ---- warp-local softmax over own 16 rows (permlane cross-row) ----
        float m = fmaxf(fmaxf(lg[0], lg[1]), fmaxf(lg[2], lg[3]));
        m = swap32_max(swap16_max(m));
        float sw = 0.f;
        for (int rg = 0; rg < 4; ++rg) {
            float p = __expf(lg[rg] - m);       // invalid rows underflow to 0
            lg[rg] = p;
            sw += p;
        }
        sw = swap32_add(swap16_add(sw));

        // ---- fv GEMM: single hi*hi pass (slot 2), reuse acc ----
        for (int nt = 0; nt < 4; ++nt) acc[nt] = zf;
        __builtin_amdgcn_s_setprio(1);
        for (int kk = 0; kk < 4; ++kk) {
            short8 bv[4];
            for (int nt = 0; nt < 4; ++nt)
                bv[nt] = *(const short8*)(wbc + ldsOff[kk*4 + nt] + 32768);  // Wv_hi slot
            for (int nt = 0; nt < 4; ++nt)
                acc[nt] = __builtin_amdgcn_mfma_f32_16x16x32_bf16(afh[kk], bv[nt], acc[nt], 0, 0, 0);
        }
        __builtin_amdgcn_s_setprio(0);

        // ---- AV: oE = sum p*silu(fv), oS = sum silu(fv) (for the +1e-7 term) ----
        float bvcv[4];
        for (int nt = 0; nt < 4; ++nt) bvcv[nt] = bvcS[h][nt*16 + a15];
        float oE[4] = {0.f,0.f,0.f,0.f}, oS[4] = {0.f,0.f,0.f,0.f};
        for (int rg = 0; rg < 4; ++rg) {
            float p = lg[rg];
            int r = w*16 + quad*4 + rg;
            float vm = (r < NL) ? 1.f : 0.f;
            for (int nt = 0; nt < 4; ++nt) {
                float sv = fsilu(acc[nt][rg] + bvcv[nt]);
                oE[nt] += p * sv;
                oS[nt] += vm * sv;
            }
        }
        for (int nt = 0; nt < 4; ++nt) {
            oE[nt] = swap32_add(swap16_add(oE[nt]));
            oS[nt] = swap32_add(swap16_add(oS[nt]));
        }
        if (lane == 0) { pS[h & 1][w][0] = m; pS[h & 1][w][1] = sw; }
        if (quad == 0)
            for (int nt = 0; nt < 4; ++nt) {
                pS[h & 1][w][2  + nt*16 + a15] = oE[nt];
                pS[h & 1][w][66 + nt*16 + a15] = oS[nt];
            }
        __syncthreads();                        // pS[h&1] ready; DMA for (h+1) drained
    }

    // ---- final merge (head 3) by warp 12 ----
    if (w == 12) {
        const int ps = (NH - 1) & 1;
        float M = pS[ps][0][0];
        for (int ww = 1; ww < NW; ++ww) M = fmaxf(M, pS[ps][ww][0]);
        float den = 0.f, num = 0.f, s1 = 0.f;
        for (int ww = 0; ww < NW; ++ww) {
            float e = __expf(pS[ps][ww][0] - M);
            den += e * pS[ps][ww][1];
            num += e * pS[ps][ww][2 + lane];
            s1  += pS[ps][ww][66 + lane];
        }
        out[(size_t)b*(NH*ND2) + (NH-1)*ND2 + lane] = num * __fdividef(1.f, den) + 1e-7f * s1;
    }
}

extern "C" void kernel_launch(void* const* d_in, const int* in_sizes, int n_in,
                              void* d_out, int out_size, void* d_ws, size_t ws_size,
                              hipStream_t stream) {
    const float* query = (const float*)d_in[0];
    const float* fact  = (const float*)d_in[1];
    const int*   maskp = (const int*)d_in[2];
    const float* mmc   = (const float*)d_in[3];
    const float* Wq1 = (const float*)d_in[4];
    const float* bq1 = (const float*)d_in[5];
    const float* Wq2 = (const float*)d_in[6];
    const float* bq2 = (const float*)d_in[7];
    const float* Wf1 = (const float*)d_in[8];
    const float* bf1 = (const float*)d_in[9];
    const float* Wf2 = (const float*)d_in[10];
    const float* bf2 = (const float*)d_in[11];
    const float* Wv1 = (const float*)d_in[12];
    const float* bv1 = (const float*)d_in[13];
    const float* Wv2 = (const float*)d_in[14];
    const float* bv2 = (const float*)d_in[15];
    const float* tau1 = (const float*)d_in[16];
    const float* tau2 = (const float*)d_in[17];

    char* ws = (char*)d_ws;
    float*          WQC  = (float*)(ws + OFF_WQC);
    float*          BQC  = (float*)(ws + OFF_BQC);
    __hip_bfloat16* WIMG = (__hip_bfloat16*)(ws + OFF_WIMG);
    float*          BFC  = (float*)(ws + OFF_BFC);
    float*          BVC  = (float*)(ws + OFF_BVC);

    k_combine<<<KC_GRID, 256, 0, stream>>>(Wq1, bq1, Wq2, bq2, Wf1, bf1, Wf2, bf2,
                                           Wv1, bv1, Wv2, bv2, WQC, BQC, WIMG, BFC, BVC);
    k_main<<<NB, NT, 0, stream>>>(fact, maskp, mmc, tau1, tau2, query, WQC, BQC,
                                  BFC, BVC, WIMG, (float*)d_out);
}